// Round 19
// baseline (145.933 us; speedup 1.0000x reference)
//
#include <hip/hip_runtime.h>
#include <math.h>

#define N_VOX (96*96*96)        // 884736 voxels per volume
#define NVOL 8                  // 4 pred + 4 target volumes
#define NEL (4*N_VOX)           // 3538944 elements in pred/target
#define PLANE (96*96)           // 9216
#define GMWORDS (N_VOX/32)      // 27648 mask words per volume
#define NFACC (4*GMWORDS/256)   // 432 fgmask blocks -> focal partial slots

// tile geometry for local CCL: full d-span x TW x TH (round-12 verified;
// r18 fused-direction worklist = 141.6us best). Rounds 13-17 lessons: (13)
// packing tiles behind one barrier cuts occupancy; (14) smaller tiles
// inflate the plane count and the bmerge tail; (15) fusing phases put the
// union-find on GLOBAL memory in one small block -> 355us; (17) LDS pair
// staging in bmerge was null. UF stays in LDS; 3-launch structure.
#define TW 8
#define TH 8
#define TILES_W 12
#define TILES_H 12
#define TILE_VOX (96*TW*TH)     // 6144
#define TILE_WORDS (TILE_VOX/32) // 192
#define MAXRUNS 3072            // max d-runs per tile (64 lines x 48)

#define NBPLANES 11             // interior tile boundaries per axis
#define NPAIRS (2*NBPLANES)     // 22 boundary plane-pairs per volume
#define FACES_PER_VOL (2*NPAIRS*PLANE) // 405504 ushorts
#define MAXR 40192              // dense roots that fit in 157 KB LDS
#define FALLR 65536             // global fallback capacity (ushort ID space)
#define SEGCAP 4608             // hard bound: <=48 starts/line * 96 lines/plane
#define HT2N 4096               // per-plane dedup hash entries (16 KB of slab)
#define MAX_PROBES 16

// workspace header (8 KB). NO host memset: fgmask block 0 zeroes the three
// accumulating counters; all else is write-before-read (poison-safe).
// Per-volume counters strided to 128 B (round-4 lesson). ROUND-9/15 LESSON:
// UF with hot roots in GLOBAL memory serializes (cross-XCD when multi-block,
// raw latency when single-block) -> UF stays in LDS with a 1024-thread block.
#define WS_ROOT  1024           // int, volume v at byte 1024+v*128
#define WS_COMP  2048           // int, volume v at byte 2048+v*128
#define WS_DONE  3072           // int, volume v at byte 3072+v*128
#define WS_VDONE 4096           // int
#define WS_PCNT  4352           // int [v*NPAIRS + f] (write-before-read)
#define WS_FACC  5120           // float [NFACC] (write-before-read)
#define WS_HDR   8192

// ---------------------------------------------------------------------------
// union-find on LDS (or gfall fallback). Labels only decrease (atomicMin).
__device__ __forceinline__ int uf_find(int* __restrict__ L, int x) {
    int r = x;
    int p = L[r];
    while (p != r) { r = p; p = L[r]; }
    if (r != x) atomicMin(&L[x], r);     // path compression (monotone-safe)
    return r;
}

// returns # destroyed self-loops (exact union events).
__device__ __forceinline__ int uf_merge(int* __restrict__ L, int l1, int l2) {
    int ev = 0;
    while (l1 != l2) {
        if (l1 < l2) { int t = l1; l1 = l2; l2 = t; }   // l1 > l2
        int l3 = atomicMin(&L[l1], l2);
        if (l3 == l1) { ev++; l1 = l2; }
        else l1 = l3;
    }
    return ev;
}

// merge on LDS run labels (concurrent-safe: atomicMin monotone)
__device__ __forceinline__ void merge_local(int* lab, int l1, int l2) {
    while (l1 != l2 && l1 != lab[l1]) l1 = lab[l1];
    while (l1 != l2 && l2 != lab[l2]) l2 = lab[l2];
    while (l1 != l2) {
        if (l1 < l2) { int t = l1; l1 = l2; l2 = t; }
        int l3 = atomicMin(&lab[l1], l2);
        l1 = (l3 == l1) ? l2 : l3;
    }
}

// run ID (0-based, tile-global) of the run containing fg voxel i:
// rank = (#run-starts at positions <= i) - 1. Lines are word-aligned
// (96 = 3x32) so a global word-ordered prefix is line-consistent.
__device__ __forceinline__ int rrank(const unsigned* __restrict__ sm,
                                     const int* __restrict__ wpf, int i) {
    int w = i >> 5, b = i & 31;
    unsigned mask = (2u << b) - 1u;      // bits 0..b inclusive (b=31 -> all)
    return wpf[w] + __popc(sm[w] & mask) - 1;
}

// ---------------------------------------------------------------------------
// Phase 0: streaming fg-mask + focal (round-10 split, round-12 self-init).
__global__ __launch_bounds__(256) void fgmask_focal(const float* __restrict__ pred,
                                                    const float* __restrict__ targ,
                                                    unsigned* __restrict__ gmask,
                                                    float* __restrict__ facc,
                                                    int* __restrict__ rootcnt,
                                                    int* __restrict__ done,
                                                    int* __restrict__ vdone) {
    __shared__ float fws[4];
    if (blockIdx.x == 0 && threadIdx.x == 0) {
        for (int v2 = 0; v2 < NVOL; v2++) { rootcnt[v2 << 5] = 0; done[v2 << 5] = 0; }
        *vdone = 0;
    }
    int tid = blockIdx.x * 256 + threadIdx.x;        // 0..110591
    int v = tid / GMWORDS;                           // pred volume 0..3
    int w = tid - v * GMWORDS;                       // word within volume
    const float4* P = (const float4*)(pred + (size_t)v * N_VOX + w * 32);
    const float4* T = (const float4*)(targ + (size_t)v * N_VOX + w * 32);
    unsigned pb = 0, tb = 0;
    float fsum = 0.0f;
    #pragma unroll
    for (int j4 = 0; j4 < 8; j4++) {
        float4 p4 = P[j4];
        float4 t4 = T[j4];
        float pv[4] = {p4.x, p4.y, p4.z, p4.w};
        float tv[4] = {t4.x, t4.y, t4.z, t4.w};
        #pragma unroll
        for (int q = 0; q < 4; q++) {
            int j = j4 * 4 + q;
            if (pv[q] > 0.0f)  pb |= (1u << j);      // sigmoid(x)>0.5
            if (tv[q] > 0.5f)  tb |= (1u << j);
            float m   = (tv[q] == 1.0f) ? -pv[q] : pv[q];
            float at  = (tv[q] == 1.0f) ? 0.25f : 0.75f;
            float e   = __expf(-fabsf(m));
            float inv = 1.0f / (1.0f + e);
            float sig = inv * ((m >= 0.0f) ? 1.0f : e);    // sigmoid(m)
            float sp  = fmaxf(m, 0.0f) + __logf(1.0f + e); // softplus(m)
            fsum += at * sig * sig * sp;
        }
    }
    gmask[(size_t)v * GMWORDS + w]       = pb;       // pred-fg volume v
    gmask[(size_t)(v + 4) * GMWORDS + w] = tb;       // targ-fg volume v+4

    for (int off = 32; off; off >>= 1) fsum += __shfl_down(fsum, off, 64);
    if ((threadIdx.x & 63) == 0) fws[threadIdx.x >> 6] = fsum;
    __syncthreads();
    if (threadIdx.x == 0)
        facc[blockIdx.x] = fws[0] + fws[1] + fws[2] + fws[3];  // plain store
}

// ---------------------------------------------------------------------------
// Phase 1: RUN-SPACE per-tile CCL in LDS. r18: fused-direction 336-item
// balanced worklist. r19: phase D dropped -- face store chases lazily
// (~770x2.5 dependent reads vs D's ~3500 + one fewer barrier).
__global__ __launch_bounds__(256) void ccl_local(const unsigned* __restrict__ gmask,
                                                 unsigned short* __restrict__ faces,
                                                 int* __restrict__ rootcnt,
                                                 int vbase) {
    __shared__ int      lab[MAXRUNS];        // 12 KB run union-find
    __shared__ unsigned fm[TILE_WORDS];      // 768 B fg bits
    __shared__ unsigned sm[TILE_WORDS];      // 768 B run-start bits
    __shared__ int      wpf[TILE_WORDS];     // 768 B exclusive start prefix
    __shared__ unsigned ovst[336];           // combined overlap-start masks
    __shared__ int      ovpf[337];           // exclusive merge prefix + total
    __shared__ int   iws[4];
    __shared__ int   gbase;

    int vloc = blockIdx.y;
    int v = vbase + vloc;
    int tile = blockIdx.x;                   // 0..143
    int tw = tile % TILES_W, th = tile / TILES_W;
    int w0 = tw * TW, h0 = th * TH;
    int tbase = h0 * PLANE + w0 * 96;        // global index of tile origin
    unsigned short* Fw = faces + (size_t)vloc * FACES_PER_VOL;  // [b][side][h*96+d]
    unsigned short* Fh = Fw + 2 * NBPLANES * PLANE;             // [b][side][w*96+d]
    const unsigned* gm = gmask + (size_t)v * GMWORDS;

    // ---- load: 192 coalesced word reads. tile word t=(lh*8+lw)*3+k maps to
    // global word tbase/32 + lh*288 + lw*3 + k (tbase divisible by 32).
    if (threadIdx.x < TILE_WORDS) {
        int t = threadIdx.x;
        int lh = t / 24, rem = t % 24;       // rem = lw*3 + k
        fm[t] = gm[(tbase >> 5) + lh * 288 + rem];
    }
    for (int r = threadIdx.x; r < MAXRUNS; r += 256) lab[r] = r;
    __syncthreads();

    // ---- A: start masks + block scan -> run ranks ----
    int cnt = 0;
    {
        unsigned st = 0;
        if (threadIdx.x < TILE_WORDS) {
            unsigned m = fm[threadIdx.x];
            unsigned carry = (threadIdx.x % 3) ? (fm[threadIdx.x - 1] >> 31) : 0u;
            st = m & ~((m << 1) | carry);
            sm[threadIdx.x] = st;
            cnt = __popc(st);
        }
    }
    int inc = cnt;
    for (int off = 1; off < 64; off <<= 1) {
        int u = __shfl_up(inc, off, 64);
        if ((threadIdx.x & 63) >= off) inc += u;
    }
    int wid = threadIdx.x >> 6;
    if ((threadIdx.x & 63) == 63) iws[wid] = inc;
    __syncthreads();
    int woff = 0;
    for (int k = 0; k < wid; k++) woff += iws[k];
    if (threadIdx.x < TILE_WORDS) wpf[threadIdx.x] = woff + inc - cnt;
    int Nr = iws[0] + iws[1] + iws[2];       // total runs (wave 3 adds none)
    __syncthreads();

    // ---- B: combined balanced-worklist merge (both directions, one pass) --
    int cnt2 = 0;
    if (threadIdx.x < 168) {
        int tt = threadIdx.x;
        {   // w-direction item
            int lh = tt / 21, rem = tt % 21, lw = rem / 3, k = rem % 3;
            int wb = (lh * 8 + lw) * 3 + k;
            int nb = wb + 3;
            unsigned ov = fm[wb] & fm[nb];
            unsigned carry = (k > 0) ? ((fm[wb - 1] & fm[nb - 1]) >> 31) : 0u;
            unsigned stm = ov & ~((ov << 1) | carry);
            ovst[2 * tt] = stm;
            cnt2 += __popc(stm);
        }
        {   // h-direction item
            int lh = tt / 24, rem = tt % 24, lw = rem / 3, k = rem % 3;
            int wb = (lh * 8 + lw) * 3 + k;
            int nb = wb + 24;
            unsigned ov = fm[wb] & fm[nb];
            unsigned carry = (k > 0) ? ((fm[wb - 1] & fm[nb - 1]) >> 31) : 0u;
            unsigned stm = ov & ~((ov << 1) | carry);
            ovst[2 * tt + 1] = stm;
            cnt2 += __popc(stm);
        }
    }
    int inc2 = cnt2;
    for (int off = 1; off < 64; off <<= 1) {
        int u = __shfl_up(inc2, off, 64);
        if ((threadIdx.x & 63) >= off) inc2 += u;
    }
    if ((threadIdx.x & 63) == 63) iws[wid] = inc2;
    __syncthreads();
    int woff2 = 0;
    for (int k = 0; k < wid; k++) woff2 += iws[k];
    if (threadIdx.x < 168) {
        int base = woff2 + inc2 - cnt2;
        ovpf[2 * threadIdx.x]     = base;
        ovpf[2 * threadIdx.x + 1] = base + __popc(ovst[2 * threadIdx.x]);
    }
    if (threadIdx.x == 0) ovpf[336] = iws[0] + iws[1] + iws[2] + iws[3];
    __syncthreads();
    int M = ovpf[336];
    for (int k2 = threadIdx.x; k2 < M; k2 += 256) {
        int lo2 = 0, hi2 = 336;              // find slot j: ovpf[j] <= k2 < ovpf[j+1]
        while (hi2 - lo2 > 1) {
            int mid = (lo2 + hi2) >> 1;
            if (ovpf[mid] <= k2) lo2 = mid; else hi2 = mid;
        }
        int j  = lo2;
        int jj = k2 - ovpf[j];
        bool wdirn = !(j & 1);
        int p = j >> 1;
        int lh, lw, kk;
        if (wdirn) { lh = p / 21; int rem = p % 21; lw = rem / 3; kk = rem % 3; }
        else       { lh = p / 24; int rem = p % 24; lw = rem / 3; kk = rem % 3; }
        int wb = (lh * 8 + lw) * 3 + kk;
        unsigned stm2 = ovst[j];
        for (int q = 0; q < jj; q++) stm2 &= stm2 - 1;   // select jj-th start
        int b = __builtin_ctz(stm2);
        int i = (wb << 5) + b;
        merge_local(lab, rrank(sm, wpf, i), rrank(sm, wpf, i + (wdirn ? 96 : 768)));
    }
    __syncthreads();

    // ---- C: count roots, dense-ID assign (full-lane strided run loops) ----
    int myroots = 0;
    for (int r = threadIdx.x; r < Nr; r += 256)
        if (lab[r] == r) myroots++;
    int s = myroots;
    for (int off = 1; off < 64; off <<= 1) {
        int u = __shfl_up(s, off, 64);
        if ((threadIdx.x & 63) >= off) s += u;
    }
    if ((threadIdx.x & 63) == 63) iws[wid] = s;
    __syncthreads();
    int wbase = 0;
    for (int k = 0; k < wid; k++) wbase += iws[k];
    if (threadIdx.x == 0)
        gbase = atomicAdd(&rootcnt[v << 5], iws[0] + iws[1] + iws[2] + iws[3]);
    __syncthreads();
    int nid = gbase + wbase + (s - myroots);
    for (int r = threadIdx.x; r < Nr; r += 256)
        if (lab[r] == r) lab[r] = ~(nid++);   // same iteration order as count
    __syncthreads();

    // ---- E: resolve + store 4 interior-adjacent faces (inline lazy chase) --
    for (int t = threadIdx.x; t < 768; t += 256) {
        int f  = t / 192;
        int g  = t % 192;
        int u  = g / 24;                     // row within face (lh or lw)
        int d4 = (g % 24) * 4;
        int i0; unsigned short* dst;
        if (f == 0) {
            if (tw == 0) continue;
            i0  = u * 768 + d4;
            dst = Fw + ((tw - 1) * 2 + 1) * PLANE + (h0 + u) * 96 + d4;
        } else if (f == 1) {
            if (tw == TILES_W - 1) continue;
            i0  = u * 768 + 7 * 96 + d4;
            dst = Fw + (tw * 2) * PLANE + (h0 + u) * 96 + d4;
        } else if (f == 2) {
            if (th == 0) continue;
            i0  = u * 96 + d4;
            dst = Fh + ((th - 1) * 2 + 1) * PLANE + (w0 + u) * 96 + d4;
        } else {
            if (th == TILES_H - 1) continue;
            i0  = 7 * 768 + u * 96 + d4;
            dst = Fh + (th * 2) * PLANE + (w0 + u) * 96 + d4;
        }
        unsigned mw = fm[i0 >> 5];           // bits d4..d4+3 in one word
        unsigned short vals[4];
        bool prevf = false;
        for (int q = 0; q < 4; q++) {
            bool fb = (mw >> ((d4 & 31) + q)) & 1;
            if (fb) {
                if (prevf) vals[q] = vals[q - 1];
                else {
                    int x = lab[rrank(sm, wpf, i0 + q)];
                    while (x >= 0) x = lab[x];        // chase to ~denseID
                    vals[q] = (unsigned short)(~x);
                }
            } else vals[q] = 0xFFFFu;
            prevf = fb;
        }
        *(ushort4*)dst = make_ushort4(vals[0], vals[1], vals[2], vals[3]);
    }
}

// ---------------------------------------------------------------------------
// Phase 2 (fused, last-block pattern): grid (22 planes x nv volumes), 1024 thr.
//  P) per-plane dedup into private segment (LDS hash, LDS counter, zero
//     global atomics).  U) 22nd-arriving block per volume: dense LDS UF over
//     the flattened unique list, exact event counting -> comp[v] = R - events.
//  F) 8th volume to finish sums the 432 focal partials + computes the loss.
// No spin-waits -> no deadlock. Release/acquire via __threadfence().
__global__ __launch_bounds__(1024) void ccl_bmerge(const unsigned short* __restrict__ faces,
                                                   unsigned* __restrict__ pairs,
                                                   int* __restrict__ pcnt,
                                                   int* __restrict__ gfall,
                                                   const int* __restrict__ rootcnt,
                                                   int* __restrict__ comp,
                                                   int* __restrict__ done,
                                                   int* __restrict__ vdone,
                                                   const float* __restrict__ facc,
                                                   float* __restrict__ out,
                                                   int vbase) {
    __shared__ int slab[MAXR];               // 157 KB: dedup hash, then UF
    __shared__ int offs[NPAIRS + 1];
    __shared__ int wsum[16];
    __shared__ float fred[16];
    __shared__ int nloc, lastf, lastv;
    unsigned* ht = (unsigned*)slab;          // first HT2N entries

    int f    = blockIdx.x;                   // plane pair 0..21
    int vloc = blockIdx.y;
    int v    = vbase + vloc;
    const unsigned short* A = faces + (size_t)vloc * FACES_PER_VOL
                                    + (size_t)(2 * f) * PLANE;
    const unsigned short* B = A + PLANE;
    unsigned* pb = pairs + ((size_t)vloc * NPAIRS + f) * SEGCAP;

    // ---- P: dedup this plane's pairs ----
    for (int i = threadIdx.x; i < HT2N; i += 1024) ht[i] = 0xFFFFFFFFu;
    if (threadIdx.x == 0) nloc = 0;
    __syncthreads();

    const int GPP = PLANE / 8;               // 1152 8-wide groups
    for (int g = threadIdx.x; g < GPP; g += 1024) {
        int e8 = g * 8;
        int4 aw = *(const int4*)(A + e8);    // 8 ushorts, coalesced 16B
        int4 bw = *(const int4*)(B + e8);
        unsigned a32[4] = {(unsigned)aw.x, (unsigned)aw.y, (unsigned)aw.z, (unsigned)aw.w};
        unsigned b32[4] = {(unsigned)bw.x, (unsigned)bw.y, (unsigned)bw.z, (unsigned)bw.w};
        bool pf = false;
        if (e8 % 96) pf = (A[e8 - 1] != 0xFFFFu) && (B[e8 - 1] != 0xFFFFu);
        #pragma unroll
        for (int q = 0; q < 8; q++) {
            unsigned av = (a32[q >> 1] >> ((q & 1) * 16)) & 0xFFFFu;
            unsigned bv = (b32[q >> 1] >> ((q & 1) * 16)) & 0xFFFFu;
            bool f2 = (av != 0xFFFFu) && (bv != 0xFFFFu);
            if (f2 && !pf && av != bv) {     // overlap-segment start along d
                unsigned lo = av < bv ? av : bv;
                unsigned hi = av < bv ? bv : av;
                unsigned key = (lo << 16) | hi;
                unsigned h = (key * 2654435761u) >> 20;   // -> 12-bit slot
                bool fresh = false;
                for (int pr = 0; pr < MAX_PROBES; pr++) {
                    unsigned prev = atomicCAS(&ht[h], 0xFFFFFFFFu, key);
                    if (prev == 0xFFFFFFFFu) { fresh = true; break; }
                    if (prev == key) break;
                    h = (h + 1) & (HT2N - 1);
                    if (pr == MAX_PROBES - 1) fresh = true;  // cap: dupe ok
                }
                if (fresh) {
                    int ix = atomicAdd(&nloc, 1);    // LDS atomic, on-CU
                    pb[ix] = key;                    // ix < SEGCAP bound
                }
            }
            pf = f2;
        }
    }
    __syncthreads();
    if (threadIdx.x == 0) {
        pcnt[v * NPAIRS + f] = nloc;
        __threadfence();                     // release: segment + pcnt visible
        int old = atomicAdd(&done[v << 5], 1);
        lastf = (old == NPAIRS - 1);
    }
    __syncthreads();
    if (!lastf) return;                      // not the last plane of volume v

    // ---- U: union for volume v (this block saw all 22 segments) ----
    __threadfence();                         // acquire
    int R = rootcnt[v << 5];
    int* lab = (R <= MAXR) ? slab : (gfall + (size_t)vloc * FALLR);
    if (threadIdx.x == 0) {
        int o = 0;
        for (int k = 0; k < NPAIRS; k++) { offs[k] = o; o += pcnt[v * NPAIRS + k]; }
        offs[NPAIRS] = o;
    }
    __syncthreads();                         // ht region dead; safe to overwrite
    for (int i = threadIdx.x; i < R; i += 1024) lab[i] = i;
    int tot = offs[NPAIRS];
    __syncthreads();

    int ev = 0;
    for (int gi = threadIdx.x; gi < tot; gi += 1024) {
        int fi = 0;
        while (offs[fi + 1] <= gi) fi++;     // <=22 LDS reads, flattened space
        unsigned key = pairs[((size_t)vloc * NPAIRS + fi) * SEGCAP + (gi - offs[fi])];
        int a = (int)(key >> 16), b = (int)(key & 0xFFFFu);
        int ra = uf_find(lab, a);
        int rb = uf_find(lab, b);
        if (ra != rb) ev += uf_merge(lab, ra, rb);
    }

    for (int off = 32; off; off >>= 1) ev += __shfl_down(ev, off, 64);
    if ((threadIdx.x & 63) == 0) wsum[threadIdx.x >> 6] = ev;
    __syncthreads();
    if (threadIdx.x == 0) {
        int tote = 0;
        for (int k = 0; k < 16; k++) tote += wsum[k];
        comp[v << 5] = R - tote;             // components of volume v
        __threadfence();                     // release comp[v]
        int old2 = atomicAdd(vdone, 1);
        lastv = (old2 == NVOL - 1);
    }
    __syncthreads();
    if (!lastv) return;

    // ---- F: final loss (all NVOL comps + focal partials now visible) ----
    __threadfence();                         // acquire
    float x = 0.0f;
    for (int i2 = threadIdx.x; i2 < NFACC; i2 += 1024) x += facc[i2];
    for (int off = 32; off; off >>= 1) x += __shfl_down(x, off, 64);
    if ((threadIdx.x & 63) == 0) fred[threadIdx.x >> 6] = x;
    __syncthreads();
    if (threadIdx.x == 0) {
        float fa = 0.0f;
        for (int k = 0; k < 16; k++) fa += fred[k];
        float c[NVOL];
        for (int w = 0; w < NVOL; w++) c[w] = (float)comp[w << 5];
        float dp0 = 0.5f * (c[0] + c[2]);
        float dp1 = 0.5f * (c[1] + c[3]);
        float dt0 = 0.5f * (c[4] + c[6]);
        float dt1 = 0.5f * (c[5] + c[7]);
        float topo = 0.5f * (fabsf(dp0 - dt0) + fabsf(dp1 - dt1));
        out[0] = fa / (float)NEL + 0.1f * topo;
    }
}

// ---------------------------------------------------------------------------
extern "C" void kernel_launch(void* const* d_in, const int* in_sizes, int n_in,
                              void* d_out, int out_size, void* d_ws, size_t ws_size,
                              hipStream_t stream) {
    const float* pred = (const float*)d_in[0];
    const float* targ = (const float*)d_in[1];
    float* out = (float*)d_out;

    // header (8 KB; self-initializing -> NO memset launch)
    int*   rootcnt = (int*)((char*)d_ws + WS_ROOT);
    int*   comp    = (int*)((char*)d_ws + WS_COMP);
    int*   done    = (int*)((char*)d_ws + WS_DONE);
    int*   vdone   = (int*)((char*)d_ws + WS_VDONE);
    int*   pcnt    = (int*)((char*)d_ws + WS_PCNT);
    float* facc    = (float*)((char*)d_ws + WS_FACC);
    unsigned* gmask = (unsigned*)((char*)d_ws + WS_HDR);         // 8 vols, 884 KB
    unsigned short* faces = (unsigned short*)(gmask + (size_t)NVOL * GMWORDS);

    size_t per_vol = (size_t)FACES_PER_VOL * 2
                   + (size_t)NPAIRS * SEGCAP * 4
                   + (size_t)FALLR * 4;
    size_t fixed   = WS_HDR + (size_t)NVOL * GMWORDS * 4;
    size_t avail   = (ws_size > fixed) ? ws_size - fixed : 0;
    int vols_per_pass = (int)(avail / per_vol);
    if (vols_per_pass > NVOL) vols_per_pass = NVOL;
    if (vols_per_pass < 1) vols_per_pass = 1;
    unsigned* pairs = (unsigned*)(faces + (size_t)vols_per_pass * FACES_PER_VOL);
    int* gfall = (int*)(pairs + (size_t)vols_per_pass * NPAIRS * SEGCAP);

    // Phase 0: streaming masks + focal; zeroes the accumulating counters.
    fgmask_focal<<<dim3(NFACC), dim3(256), 0, stream>>>(pred, targ, gmask, facc,
                                                        rootcnt, done, vdone);

    for (int vbase = 0; vbase < NVOL; vbase += vols_per_pass) {
        int nv = NVOL - vbase;
        if (nv > vols_per_pass) nv = vols_per_pass;
        dim3 tgrid(TILES_W * TILES_H, nv);
        ccl_local<<<tgrid, dim3(256), 0, stream>>>(gmask, faces, rootcnt, vbase);
        dim3 mgrid(NPAIRS, nv);
        ccl_bmerge<<<mgrid, dim3(1024), 0, stream>>>(faces, pairs, pcnt, gfall,
                                                     rootcnt, comp, done, vdone,
                                                     facc, out, vbase);
    }
}

// Round 20
// 140.543 us; speedup vs baseline: 1.0383x; 1.0383x over previous
//
#include <hip/hip_runtime.h>
#include <math.h>

#define N_VOX (96*96*96)        // 884736 voxels per volume
#define NVOL 8                  // 4 pred + 4 target volumes
#define NEL (4*N_VOX)           // 3538944 elements in pred/target
#define PLANE (96*96)           // 9216
#define GMWORDS (N_VOX/32)      // 27648 mask words per volume
#define NFACC (4*GMWORDS/256)   // 432 fgmask blocks -> focal partial slots

// tile geometry for local CCL: full d-span x TW x TH. FINAL (r20): the r18
// artifact (141.6us verified best; baseline was 208.8). Ledger: launch gaps
// ~40us (r15 fusion alternative = 355us), ccl_local ~41us (r13/r14/r19
// alternatives null/regressed), ccl_bmerge ~44us (r17 staging null; r9/r15
// global-UF alternatives catastrophic), fgmask ~8us (near HBM-efficient).
#define TW 8
#define TH 8
#define TILES_W 12
#define TILES_H 12
#define TILE_VOX (96*TW*TH)     // 6144
#define TILE_WORDS (TILE_VOX/32) // 192
#define MAXRUNS 3072            // max d-runs per tile (64 lines x 48)

#define NBPLANES 11             // interior tile boundaries per axis
#define NPAIRS (2*NBPLANES)     // 22 boundary plane-pairs per volume
#define FACES_PER_VOL (2*NPAIRS*PLANE) // 405504 ushorts
#define MAXR 40192              // dense roots that fit in 157 KB LDS
#define FALLR 65536             // global fallback capacity (ushort ID space)
#define SEGCAP 4608             // hard bound: <=48 starts/line * 96 lines/plane
#define HT2N 4096               // per-plane dedup hash entries (16 KB of slab)
#define MAX_PROBES 16

// workspace header (8 KB). NO host memset: fgmask block 0 zeroes the three
// accumulating counters; all else is write-before-read (poison-safe).
// Per-volume counters strided to 128 B (round-4 lesson). ROUND-9/15 LESSON:
// UF with hot roots in GLOBAL memory serializes (cross-XCD when multi-block,
// raw latency when single-block) -> UF stays in LDS with a 1024-thread block.
#define WS_ROOT  1024           // int, volume v at byte 1024+v*128
#define WS_COMP  2048           // int, volume v at byte 2048+v*128
#define WS_DONE  3072           // int, volume v at byte 3072+v*128
#define WS_VDONE 4096           // int
#define WS_PCNT  4352           // int [v*NPAIRS + f] (write-before-read)
#define WS_FACC  5120           // float [NFACC] (write-before-read)
#define WS_HDR   8192

// ---------------------------------------------------------------------------
// union-find on LDS (or gfall fallback). Labels only decrease (atomicMin).
__device__ __forceinline__ int uf_find(int* __restrict__ L, int x) {
    int r = x;
    int p = L[r];
    while (p != r) { r = p; p = L[r]; }
    if (r != x) atomicMin(&L[x], r);     // path compression (monotone-safe)
    return r;
}

// returns # destroyed self-loops (exact union events).
__device__ __forceinline__ int uf_merge(int* __restrict__ L, int l1, int l2) {
    int ev = 0;
    while (l1 != l2) {
        if (l1 < l2) { int t = l1; l1 = l2; l2 = t; }   // l1 > l2
        int l3 = atomicMin(&L[l1], l2);
        if (l3 == l1) { ev++; l1 = l2; }
        else l1 = l3;
    }
    return ev;
}

// merge on LDS run labels (concurrent-safe: atomicMin monotone)
__device__ __forceinline__ void merge_local(int* lab, int l1, int l2) {
    while (l1 != l2 && l1 != lab[l1]) l1 = lab[l1];
    while (l1 != l2 && l2 != lab[l2]) l2 = lab[l2];
    while (l1 != l2) {
        if (l1 < l2) { int t = l1; l1 = l2; l2 = t; }
        int l3 = atomicMin(&lab[l1], l2);
        l1 = (l3 == l1) ? l2 : l3;
    }
}

// run ID (0-based, tile-global) of the run containing fg voxel i:
// rank = (#run-starts at positions <= i) - 1. Lines are word-aligned
// (96 = 3x32) so a global word-ordered prefix is line-consistent.
__device__ __forceinline__ int rrank(const unsigned* __restrict__ sm,
                                     const int* __restrict__ wpf, int i) {
    int w = i >> 5, b = i & 31;
    unsigned mask = (2u << b) - 1u;      // bits 0..b inclusive (b=31 -> all)
    return wpf[w] + __popc(sm[w] & mask) - 1;
}

// ---------------------------------------------------------------------------
// Phase 0: streaming fg-mask + focal (round-10 split, round-12 self-init).
__global__ __launch_bounds__(256) void fgmask_focal(const float* __restrict__ pred,
                                                    const float* __restrict__ targ,
                                                    unsigned* __restrict__ gmask,
                                                    float* __restrict__ facc,
                                                    int* __restrict__ rootcnt,
                                                    int* __restrict__ done,
                                                    int* __restrict__ vdone) {
    __shared__ float fws[4];
    if (blockIdx.x == 0 && threadIdx.x == 0) {
        for (int v2 = 0; v2 < NVOL; v2++) { rootcnt[v2 << 5] = 0; done[v2 << 5] = 0; }
        *vdone = 0;
    }
    int tid = blockIdx.x * 256 + threadIdx.x;        // 0..110591
    int v = tid / GMWORDS;                           // pred volume 0..3
    int w = tid - v * GMWORDS;                       // word within volume
    const float4* P = (const float4*)(pred + (size_t)v * N_VOX + w * 32);
    const float4* T = (const float4*)(targ + (size_t)v * N_VOX + w * 32);
    unsigned pb = 0, tb = 0;
    float fsum = 0.0f;
    #pragma unroll
    for (int j4 = 0; j4 < 8; j4++) {
        float4 p4 = P[j4];
        float4 t4 = T[j4];
        float pv[4] = {p4.x, p4.y, p4.z, p4.w};
        float tv[4] = {t4.x, t4.y, t4.z, t4.w};
        #pragma unroll
        for (int q = 0; q < 4; q++) {
            int j = j4 * 4 + q;
            if (pv[q] > 0.0f)  pb |= (1u << j);      // sigmoid(x)>0.5
            if (tv[q] > 0.5f)  tb |= (1u << j);
            float m   = (tv[q] == 1.0f) ? -pv[q] : pv[q];
            float at  = (tv[q] == 1.0f) ? 0.25f : 0.75f;
            float e   = __expf(-fabsf(m));
            float inv = 1.0f / (1.0f + e);
            float sig = inv * ((m >= 0.0f) ? 1.0f : e);    // sigmoid(m)
            float sp  = fmaxf(m, 0.0f) + __logf(1.0f + e); // softplus(m)
            fsum += at * sig * sig * sp;
        }
    }
    gmask[(size_t)v * GMWORDS + w]       = pb;       // pred-fg volume v
    gmask[(size_t)(v + 4) * GMWORDS + w] = tb;       // targ-fg volume v+4

    for (int off = 32; off; off >>= 1) fsum += __shfl_down(fsum, off, 64);
    if ((threadIdx.x & 63) == 0) fws[threadIdx.x >> 6] = fsum;
    __syncthreads();
    if (threadIdx.x == 0)
        facc[blockIdx.x] = fws[0] + fws[1] + fws[2] + fws[3];  // plain store
}

// ---------------------------------------------------------------------------
// Phase 1: RUN-SPACE per-tile CCL in LDS. r18: fused-direction 336-item
// balanced worklist (w-item at slot 2t, h-item at slot 2t+1 -> monotone
// ovpf) -- one scan + 3 barriers; concurrent UF makes cross-dir merges safe.
__global__ __launch_bounds__(256) void ccl_local(const unsigned* __restrict__ gmask,
                                                 unsigned short* __restrict__ faces,
                                                 int* __restrict__ rootcnt,
                                                 int vbase) {
    __shared__ int      lab[MAXRUNS];        // 12 KB run union-find
    __shared__ unsigned fm[TILE_WORDS];      // 768 B fg bits
    __shared__ unsigned sm[TILE_WORDS];      // 768 B run-start bits
    __shared__ int      wpf[TILE_WORDS];     // 768 B exclusive start prefix
    __shared__ unsigned ovst[336];           // combined overlap-start masks
    __shared__ int      ovpf[337];           // exclusive merge prefix + total
    __shared__ int   iws[4];
    __shared__ int   gbase;

    int vloc = blockIdx.y;
    int v = vbase + vloc;
    int tile = blockIdx.x;                   // 0..143
    int tw = tile % TILES_W, th = tile / TILES_W;
    int w0 = tw * TW, h0 = th * TH;
    int tbase = h0 * PLANE + w0 * 96;        // global index of tile origin
    unsigned short* Fw = faces + (size_t)vloc * FACES_PER_VOL;  // [b][side][h*96+d]
    unsigned short* Fh = Fw + 2 * NBPLANES * PLANE;             // [b][side][w*96+d]
    const unsigned* gm = gmask + (size_t)v * GMWORDS;

    // ---- load: 192 coalesced word reads. tile word t=(lh*8+lw)*3+k maps to
    // global word tbase/32 + lh*288 + lw*3 + k (tbase divisible by 32).
    if (threadIdx.x < TILE_WORDS) {
        int t = threadIdx.x;
        int lh = t / 24, rem = t % 24;       // rem = lw*3 + k
        fm[t] = gm[(tbase >> 5) + lh * 288 + rem];
    }
    for (int r = threadIdx.x; r < MAXRUNS; r += 256) lab[r] = r;
    __syncthreads();

    // ---- A: start masks + block scan -> run ranks ----
    int cnt = 0;
    {
        unsigned st = 0;
        if (threadIdx.x < TILE_WORDS) {
            unsigned m = fm[threadIdx.x];
            unsigned carry = (threadIdx.x % 3) ? (fm[threadIdx.x - 1] >> 31) : 0u;
            st = m & ~((m << 1) | carry);
            sm[threadIdx.x] = st;
            cnt = __popc(st);
        }
    }
    int inc = cnt;
    for (int off = 1; off < 64; off <<= 1) {
        int u = __shfl_up(inc, off, 64);
        if ((threadIdx.x & 63) >= off) inc += u;
    }
    int wid = threadIdx.x >> 6;
    if ((threadIdx.x & 63) == 63) iws[wid] = inc;
    __syncthreads();
    int woff = 0;
    for (int k = 0; k < wid; k++) woff += iws[k];
    if (threadIdx.x < TILE_WORDS) wpf[threadIdx.x] = woff + inc - cnt;
    int Nr = iws[0] + iws[1] + iws[2];       // total runs (wave 3 adds none)
    __syncthreads();

    // ---- B: combined balanced-worklist merge (both directions, one pass) --
    int cnt2 = 0;
    if (threadIdx.x < 168) {
        int tt = threadIdx.x;
        {   // w-direction item
            int lh = tt / 21, rem = tt % 21, lw = rem / 3, k = rem % 3;
            int wb = (lh * 8 + lw) * 3 + k;
            int nb = wb + 3;
            unsigned ov = fm[wb] & fm[nb];
            unsigned carry = (k > 0) ? ((fm[wb - 1] & fm[nb - 1]) >> 31) : 0u;
            unsigned stm = ov & ~((ov << 1) | carry);
            ovst[2 * tt] = stm;
            cnt2 += __popc(stm);
        }
        {   // h-direction item
            int lh = tt / 24, rem = tt % 24, lw = rem / 3, k = rem % 3;
            int wb = (lh * 8 + lw) * 3 + k;
            int nb = wb + 24;
            unsigned ov = fm[wb] & fm[nb];
            unsigned carry = (k > 0) ? ((fm[wb - 1] & fm[nb - 1]) >> 31) : 0u;
            unsigned stm = ov & ~((ov << 1) | carry);
            ovst[2 * tt + 1] = stm;
            cnt2 += __popc(stm);
        }
    }
    int inc2 = cnt2;
    for (int off = 1; off < 64; off <<= 1) {
        int u = __shfl_up(inc2, off, 64);
        if ((threadIdx.x & 63) >= off) inc2 += u;
    }
    if ((threadIdx.x & 63) == 63) iws[wid] = inc2;
    __syncthreads();
    int woff2 = 0;
    for (int k = 0; k < wid; k++) woff2 += iws[k];
    if (threadIdx.x < 168) {
        int base = woff2 + inc2 - cnt2;
        ovpf[2 * threadIdx.x]     = base;
        ovpf[2 * threadIdx.x + 1] = base + __popc(ovst[2 * threadIdx.x]);
    }
    if (threadIdx.x == 0) ovpf[336] = iws[0] + iws[1] + iws[2] + iws[3];
    __syncthreads();
    int M = ovpf[336];
    for (int k2 = threadIdx.x; k2 < M; k2 += 256) {
        int lo2 = 0, hi2 = 336;              // find slot j: ovpf[j] <= k2 < ovpf[j+1]
        while (hi2 - lo2 > 1) {
            int mid = (lo2 + hi2) >> 1;
            if (ovpf[mid] <= k2) lo2 = mid; else hi2 = mid;
        }
        int j  = lo2;
        int jj = k2 - ovpf[j];
        bool wdirn = !(j & 1);
        int p = j >> 1;
        int lh, lw, kk;
        if (wdirn) { lh = p / 21; int rem = p % 21; lw = rem / 3; kk = rem % 3; }
        else       { lh = p / 24; int rem = p % 24; lw = rem / 3; kk = rem % 3; }
        int wb = (lh * 8 + lw) * 3 + kk;
        unsigned stm2 = ovst[j];
        for (int q = 0; q < jj; q++) stm2 &= stm2 - 1;   // select jj-th start
        int b = __builtin_ctz(stm2);
        int i = (wb << 5) + b;
        merge_local(lab, rrank(sm, wpf, i), rrank(sm, wpf, i + (wdirn ? 96 : 768)));
    }
    __syncthreads();

    // ---- C: count roots, dense-ID assign (full-lane strided run loops) ----
    int myroots = 0;
    for (int r = threadIdx.x; r < Nr; r += 256)
        if (lab[r] == r) myroots++;
    int s = myroots;
    for (int off = 1; off < 64; off <<= 1) {
        int u = __shfl_up(s, off, 64);
        if ((threadIdx.x & 63) >= off) s += u;
    }
    if ((threadIdx.x & 63) == 63) iws[wid] = s;
    __syncthreads();
    int wbase = 0;
    for (int k = 0; k < wid; k++) wbase += iws[k];
    if (threadIdx.x == 0)
        gbase = atomicAdd(&rootcnt[v << 5], iws[0] + iws[1] + iws[2] + iws[3]);
    __syncthreads();
    int nid = gbase + wbase + (s - myroots);
    for (int r = threadIdx.x; r < Nr; r += 256)
        if (lab[r] == r) lab[r] = ~(nid++);   // same iteration order as count
    __syncthreads();

    // ---- D: flatten non-roots to ~denseID (monotone, race-safe) ----
    for (int r = threadIdx.x; r < Nr; r += 256) {
        int p = lab[r];
        if (p >= 0) {
            int q2 = lab[p];
            while (q2 >= 0) { p = q2; q2 = lab[p]; }
            lab[r] = q2;
        }
    }
    __syncthreads();

    // ---- E: resolve + store the 4 interior-adjacent faces (ushort4) ----
    for (int t = threadIdx.x; t < 768; t += 256) {
        int f  = t / 192;
        int g  = t % 192;
        int u  = g / 24;                     // row within face (lh or lw)
        int d4 = (g % 24) * 4;
        int i0; unsigned short* dst;
        if (f == 0) {
            if (tw == 0) continue;
            i0  = u * 768 + d4;
            dst = Fw + ((tw - 1) * 2 + 1) * PLANE + (h0 + u) * 96 + d4;
        } else if (f == 1) {
            if (tw == TILES_W - 1) continue;
            i0  = u * 768 + 7 * 96 + d4;
            dst = Fw + (tw * 2) * PLANE + (h0 + u) * 96 + d4;
        } else if (f == 2) {
            if (th == 0) continue;
            i0  = u * 96 + d4;
            dst = Fh + ((th - 1) * 2 + 1) * PLANE + (w0 + u) * 96 + d4;
        } else {
            if (th == TILES_H - 1) continue;
            i0  = 7 * 768 + u * 96 + d4;
            dst = Fh + (th * 2) * PLANE + (w0 + u) * 96 + d4;
        }
        unsigned mw = fm[i0 >> 5];           // bits d4..d4+3 in one word
        unsigned short vals[4];
        bool prevf = false;
        for (int q = 0; q < 4; q++) {
            bool fb = (mw >> ((d4 & 31) + q)) & 1;
            if (fb) vals[q] = prevf ? vals[q - 1]
                                    : (unsigned short)(~lab[rrank(sm, wpf, i0 + q)]);
            else vals[q] = 0xFFFFu;
            prevf = fb;
        }
        *(ushort4*)dst = make_ushort4(vals[0], vals[1], vals[2], vals[3]);
    }
}

// ---------------------------------------------------------------------------
// Phase 2 (fused, last-block pattern): grid (22 planes x nv volumes), 1024 thr.
//  P) per-plane dedup into private segment (LDS hash, LDS counter, zero
//     global atomics).  U) 22nd-arriving block per volume: dense LDS UF over
//     the flattened unique list, exact event counting -> comp[v] = R - events.
//  F) 8th volume to finish sums the 432 focal partials + computes the loss.
// No spin-waits -> no deadlock. Release/acquire via __threadfence().
__global__ __launch_bounds__(1024) void ccl_bmerge(const unsigned short* __restrict__ faces,
                                                   unsigned* __restrict__ pairs,
                                                   int* __restrict__ pcnt,
                                                   int* __restrict__ gfall,
                                                   const int* __restrict__ rootcnt,
                                                   int* __restrict__ comp,
                                                   int* __restrict__ done,
                                                   int* __restrict__ vdone,
                                                   const float* __restrict__ facc,
                                                   float* __restrict__ out,
                                                   int vbase) {
    __shared__ int slab[MAXR];               // 157 KB: dedup hash, then UF
    __shared__ int offs[NPAIRS + 1];
    __shared__ int wsum[16];
    __shared__ float fred[16];
    __shared__ int nloc, lastf, lastv;
    unsigned* ht = (unsigned*)slab;          // first HT2N entries

    int f    = blockIdx.x;                   // plane pair 0..21
    int vloc = blockIdx.y;
    int v    = vbase + vloc;
    const unsigned short* A = faces + (size_t)vloc * FACES_PER_VOL
                                    + (size_t)(2 * f) * PLANE;
    const unsigned short* B = A + PLANE;
    unsigned* pb = pairs + ((size_t)vloc * NPAIRS + f) * SEGCAP;

    // ---- P: dedup this plane's pairs ----
    for (int i = threadIdx.x; i < HT2N; i += 1024) ht[i] = 0xFFFFFFFFu;
    if (threadIdx.x == 0) nloc = 0;
    __syncthreads();

    const int GPP = PLANE / 8;               // 1152 8-wide groups
    for (int g = threadIdx.x; g < GPP; g += 1024) {
        int e8 = g * 8;
        int4 aw = *(const int4*)(A + e8);    // 8 ushorts, coalesced 16B
        int4 bw = *(const int4*)(B + e8);
        unsigned a32[4] = {(unsigned)aw.x, (unsigned)aw.y, (unsigned)aw.z, (unsigned)aw.w};
        unsigned b32[4] = {(unsigned)bw.x, (unsigned)bw.y, (unsigned)bw.z, (unsigned)bw.w};
        bool pf = false;
        if (e8 % 96) pf = (A[e8 - 1] != 0xFFFFu) && (B[e8 - 1] != 0xFFFFu);
        #pragma unroll
        for (int q = 0; q < 8; q++) {
            unsigned av = (a32[q >> 1] >> ((q & 1) * 16)) & 0xFFFFu;
            unsigned bv = (b32[q >> 1] >> ((q & 1) * 16)) & 0xFFFFu;
            bool f2 = (av != 0xFFFFu) && (bv != 0xFFFFu);
            if (f2 && !pf && av != bv) {     // overlap-segment start along d
                unsigned lo = av < bv ? av : bv;
                unsigned hi = av < bv ? bv : av;
                unsigned key = (lo << 16) | hi;
                unsigned h = (key * 2654435761u) >> 20;   // -> 12-bit slot
                bool fresh = false;
                for (int pr = 0; pr < MAX_PROBES; pr++) {
                    unsigned prev = atomicCAS(&ht[h], 0xFFFFFFFFu, key);
                    if (prev == 0xFFFFFFFFu) { fresh = true; break; }
                    if (prev == key) break;
                    h = (h + 1) & (HT2N - 1);
                    if (pr == MAX_PROBES - 1) fresh = true;  // cap: dupe ok
                }
                if (fresh) {
                    int ix = atomicAdd(&nloc, 1);    // LDS atomic, on-CU
                    pb[ix] = key;                    // ix < SEGCAP bound
                }
            }
            pf = f2;
        }
    }
    __syncthreads();
    if (threadIdx.x == 0) {
        pcnt[v * NPAIRS + f] = nloc;
        __threadfence();                     // release: segment + pcnt visible
        int old = atomicAdd(&done[v << 5], 1);
        lastf = (old == NPAIRS - 1);
    }
    __syncthreads();
    if (!lastf) return;                      // not the last plane of volume v

    // ---- U: union for volume v (this block saw all 22 segments) ----
    __threadfence();                         // acquire
    int R = rootcnt[v << 5];
    int* lab = (R <= MAXR) ? slab : (gfall + (size_t)vloc * FALLR);
    if (threadIdx.x == 0) {
        int o = 0;
        for (int k = 0; k < NPAIRS; k++) { offs[k] = o; o += pcnt[v * NPAIRS + k]; }
        offs[NPAIRS] = o;
    }
    __syncthreads();                         // ht region dead; safe to overwrite
    for (int i = threadIdx.x; i < R; i += 1024) lab[i] = i;
    int tot = offs[NPAIRS];
    __syncthreads();

    int ev = 0;
    for (int gi = threadIdx.x; gi < tot; gi += 1024) {
        int fi = 0;
        while (offs[fi + 1] <= gi) fi++;     // <=22 LDS reads, flattened space
        unsigned key = pairs[((size_t)vloc * NPAIRS + fi) * SEGCAP + (gi - offs[fi])];
        int a = (int)(key >> 16), b = (int)(key & 0xFFFFu);
        int ra = uf_find(lab, a);
        int rb = uf_find(lab, b);
        if (ra != rb) ev += uf_merge(lab, ra, rb);
    }

    for (int off = 32; off; off >>= 1) ev += __shfl_down(ev, off, 64);
    if ((threadIdx.x & 63) == 0) wsum[threadIdx.x >> 6] = ev;
    __syncthreads();
    if (threadIdx.x == 0) {
        int tote = 0;
        for (int k = 0; k < 16; k++) tote += wsum[k];
        comp[v << 5] = R - tote;             // components of volume v
        __threadfence();                     // release comp[v]
        int old2 = atomicAdd(vdone, 1);
        lastv = (old2 == NVOL - 1);
    }
    __syncthreads();
    if (!lastv) return;

    // ---- F: final loss (all NVOL comps + focal partials now visible) ----
    __threadfence();                         // acquire
    float x = 0.0f;
    for (int i2 = threadIdx.x; i2 < NFACC; i2 += 1024) x += facc[i2];
    for (int off = 32; off; off >>= 1) x += __shfl_down(x, off, 64);
    if ((threadIdx.x & 63) == 0) fred[threadIdx.x >> 6] = x;
    __syncthreads();
    if (threadIdx.x == 0) {
        float fa = 0.0f;
        for (int k = 0; k < 16; k++) fa += fred[k];
        float c[NVOL];
        for (int w = 0; w < NVOL; w++) c[w] = (float)comp[w << 5];
        float dp0 = 0.5f * (c[0] + c[2]);
        float dp1 = 0.5f * (c[1] + c[3]);
        float dt0 = 0.5f * (c[4] + c[6]);
        float dt1 = 0.5f * (c[5] + c[7]);
        float topo = 0.5f * (fabsf(dp0 - dt0) + fabsf(dp1 - dt1));
        out[0] = fa / (float)NEL + 0.1f * topo;
    }
}

// ---------------------------------------------------------------------------
extern "C" void kernel_launch(void* const* d_in, const int* in_sizes, int n_in,
                              void* d_out, int out_size, void* d_ws, size_t ws_size,
                              hipStream_t stream) {
    const float* pred = (const float*)d_in[0];
    const float* targ = (const float*)d_in[1];
    float* out = (float*)d_out;

    // header (8 KB; self-initializing -> NO memset launch)
    int*   rootcnt = (int*)((char*)d_ws + WS_ROOT);
    int*   comp    = (int*)((char*)d_ws + WS_COMP);
    int*   done    = (int*)((char*)d_ws + WS_DONE);
    int*   vdone   = (int*)((char*)d_ws + WS_VDONE);
    int*   pcnt    = (int*)((char*)d_ws + WS_PCNT);
    float* facc    = (float*)((char*)d_ws + WS_FACC);
    unsigned* gmask = (unsigned*)((char*)d_ws + WS_HDR);         // 8 vols, 884 KB
    unsigned short* faces = (unsigned short*)(gmask + (size_t)NVOL * GMWORDS);

    size_t per_vol = (size_t)FACES_PER_VOL * 2
                   + (size_t)NPAIRS * SEGCAP * 4
                   + (size_t)FALLR * 4;
    size_t fixed   = WS_HDR + (size_t)NVOL * GMWORDS * 4;
    size_t avail   = (ws_size > fixed) ? ws_size - fixed : 0;
    int vols_per_pass = (int)(avail / per_vol);
    if (vols_per_pass > NVOL) vols_per_pass = NVOL;
    if (vols_per_pass < 1) vols_per_pass = 1;
    unsigned* pairs = (unsigned*)(faces + (size_t)vols_per_pass * FACES_PER_VOL);
    int* gfall = (int*)(pairs + (size_t)vols_per_pass * NPAIRS * SEGCAP);

    // Phase 0: streaming masks + focal; zeroes the accumulating counters.
    fgmask_focal<<<dim3(NFACC), dim3(256), 0, stream>>>(pred, targ, gmask, facc,
                                                        rootcnt, done, vdone);

    for (int vbase = 0; vbase < NVOL; vbase += vols_per_pass) {
        int nv = NVOL - vbase;
        if (nv > vols_per_pass) nv = vols_per_pass;
        dim3 tgrid(TILES_W * TILES_H, nv);
        ccl_local<<<tgrid, dim3(256), 0, stream>>>(gmask, faces, rootcnt, vbase);
        dim3 mgrid(NPAIRS, nv);
        ccl_bmerge<<<mgrid, dim3(1024), 0, stream>>>(faces, pairs, pcnt, gfall,
                                                     rootcnt, comp, done, vdone,
                                                     facc, out, vbase);
    }
}